// Round 4
// baseline (362.020 us; speedup 1.0000x reference)
//
#include <hip/hip_runtime.h>

#define NPT    16384
#define TOTP   32768          // B*N
#define FD     128
#define NROWS  (TOTP*4)       // 131072
#define NTILES (NROWS/32)     // 4096 step tiles (8 points x 4 nbrs)
#define NGRP   (NTILES/2)     // 2048
#define FTILES (TOTP/32)      // 1024
#define FGRP   (FTILES/2)     // 512

typedef unsigned short u16;
typedef __attribute__((ext_vector_type(8))) short bf16x8;
typedef __attribute__((ext_vector_type(4))) float f32x4;

__device__ __forceinline__ float bf2f(u16 u) {
    union { unsigned int i; float f; } v; v.i = ((unsigned int)u) << 16; return v.f;
}
__device__ __forceinline__ u16 f2bf(float f) {
    union { float f; unsigned int i; } v; v.f = f;
    unsigned int u = v.i;
    u = u + 0x7FFFu + ((u >> 16) & 1u);   // RNE
    return (u16)(u >> 16);
}
// 32x128 bf16 tile, row stride 256B, G4 XOR swizzle (conflict-free b128 col reads)
__device__ __forceinline__ int swz(int row, int colbyte) {
    return row*256 + (colbyte ^ ((row & 7) << 4));
}

// ---------------------------------------------------------------------------
// fproj[p][j] = b0[j] + feat[p] @ W0[3:]   (feat = relu(pcl@Wf1+bf1)@Wf2+bf2)
// 2 tiles (64 points) per barrier group; 4 waves col-split; weights in regs.
// ---------------------------------------------------------------------------
__global__ __launch_bounds__(256, 2) void fproj_mfma(
    const float* __restrict__ pcl, const float* __restrict__ Wf1,
    const float* __restrict__ bf1, const float* __restrict__ Wf2,
    const float* __restrict__ bf2, const float* __restrict__ W0,
    const float* __restrict__ b0, u16* __restrict__ fproj)
{
    __shared__ __align__(16) char hA[16384];
    __shared__ __align__(16) char hB[16384];
    const int tid = threadIdx.x, wid = tid >> 6, l = tid & 63;
    const int l15 = l & 15, l4 = l >> 4;
    const int colb = wid * 32;

    bf16x8 wfA[2][4], wfB[2][4];
    #pragma unroll
    for (int ntg = 0; ntg < 2; ++ntg)
        #pragma unroll
        for (int kk = 0; kk < 4; ++kk) {
            bf16x8 fa, fb;
            #pragma unroll
            for (int e = 0; e < 8; ++e) {
                int k = kk*32 + l4*8 + e;
                int n = colb + ntg*16 + l15;
                fa[e] = (short)f2bf(Wf2[k*FD + n]);
                fb[e] = (short)f2bf(W0[(3+k)*FD + n]);
            }
            wfA[ntg][kk] = fa; wfB[ntg][kk] = fb;
        }
    float wf1c[3][2], bf1v[2], bf2v[2], b0v[2];
    #pragma unroll
    for (int ntg = 0; ntg < 2; ++ntg) {
        int col = colb + ntg*16 + l15;
        wf1c[0][ntg] = Wf1[0*FD+col];
        wf1c[1][ntg] = Wf1[1*FD+col];
        wf1c[2][ntg] = Wf1[2*FD+col];
        bf1v[ntg] = bf1[col]; bf2v[ntg] = bf2[col]; b0v[ntg] = b0[col];
    }

    for (int grp = blockIdx.x; grp < FGRP; grp += gridDim.x) {
        // ---- P0: t = relu(pcl@Wf1+bf1) -> hA (both tiles) ----
        #pragma unroll
        for (int t = 0; t < 2; ++t) {
            char* hAt = hA + t*8192;
            const int pt0 = (grp*2 + t)*32;
            #pragma unroll
            for (int rt = 0; rt < 2; ++rt)
                #pragma unroll
                for (int reg = 0; reg < 4; ++reg) {
                    int row = rt*16 + l4*4 + reg;
                    int p = pt0 + row;
                    float px = pcl[p*3+0], py = pcl[p*3+1], pz = pcl[p*3+2];
                    #pragma unroll
                    for (int ntg = 0; ntg < 2; ++ntg) {
                        float tv = bf1v[ntg] + px*wf1c[0][ntg] + py*wf1c[1][ntg] + pz*wf1c[2][ntg];
                        tv = fmaxf(tv, 0.f);
                        int col = colb + ntg*16 + l15;
                        *(u16*)(hAt + swz(row, col*2)) = f2bf(tv);
                    }
                }
        }
        __syncthreads();
        // ---- P1: feat = t @ Wf2 + bf2 -> hB ----
        #pragma unroll
        for (int t = 0; t < 2; ++t) {
            char* hAt = hA + t*8192;
            char* hBt = hB + t*8192;
            bf16x8 a[2][4];
            #pragma unroll
            for (int rt = 0; rt < 2; ++rt)
                #pragma unroll
                for (int kk = 0; kk < 4; ++kk)
                    a[rt][kk] = *(const bf16x8*)(hAt + swz(rt*16 + l15, kk*64 + l4*16));
            #pragma unroll
            for (int ntg = 0; ntg < 2; ++ntg) {
                f32x4 acc0 = {bf2v[ntg],bf2v[ntg],bf2v[ntg],bf2v[ntg]};
                f32x4 acc1 = acc0;
                #pragma unroll
                for (int kk = 0; kk < 4; ++kk) {
                    acc0 = __builtin_amdgcn_mfma_f32_16x16x32_bf16(a[0][kk], wfA[ntg][kk], acc0, 0,0,0);
                    acc1 = __builtin_amdgcn_mfma_f32_16x16x32_bf16(a[1][kk], wfA[ntg][kk], acc1, 0,0,0);
                }
                int col = colb + ntg*16 + l15;
                #pragma unroll
                for (int reg = 0; reg < 4; ++reg) {
                    *(u16*)(hBt + swz(l4*4+reg,    col*2)) = f2bf(acc0[reg]);
                    *(u16*)(hBt + swz(16+l4*4+reg, col*2)) = f2bf(acc1[reg]);
                }
            }
        }
        __syncthreads();
        // ---- P2: fproj = feat @ W0[3:] + b0 -> global ----
        #pragma unroll
        for (int t = 0; t < 2; ++t) {
            char* hBt = hB + t*8192;
            const int pt0 = (grp*2 + t)*32;
            bf16x8 a[2][4];
            #pragma unroll
            for (int rt = 0; rt < 2; ++rt)
                #pragma unroll
                for (int kk = 0; kk < 4; ++kk)
                    a[rt][kk] = *(const bf16x8*)(hBt + swz(rt*16 + l15, kk*64 + l4*16));
            #pragma unroll
            for (int ntg = 0; ntg < 2; ++ntg) {
                f32x4 acc0 = {b0v[ntg],b0v[ntg],b0v[ntg],b0v[ntg]};
                f32x4 acc1 = acc0;
                #pragma unroll
                for (int kk = 0; kk < 4; ++kk) {
                    acc0 = __builtin_amdgcn_mfma_f32_16x16x32_bf16(a[0][kk], wfB[ntg][kk], acc0, 0,0,0);
                    acc1 = __builtin_amdgcn_mfma_f32_16x16x32_bf16(a[1][kk], wfB[ntg][kk], acc1, 0,0,0);
                }
                int col = colb + ntg*16 + l15;
                #pragma unroll
                for (int reg = 0; reg < 4; ++reg) {
                    fproj[(size_t)(pt0 + l4*4+reg)*FD + col]      = f2bf(acc0[reg]);
                    fproj[(size_t)(pt0 + 16 + l4*4+reg)*FD + col] = f2bf(acc1[reg]);
                }
            }
        }
        __syncthreads();   // guard hB before next P1 (hA guarded by P0-end barrier)
    }
}

// ---------------------------------------------------------------------------
// One denoise step: writes s*(grad+bo) to dense grad buffer (no atomics).
// 2 tiles per barrier group; 4 waves col-split; Wb/Wo register-resident.
// ---------------------------------------------------------------------------
__global__ __launch_bounds__(256, 3) void step_mfma(
    const float* __restrict__ cur, const float* __restrict__ noisy,
    const u16* __restrict__ fproj, const float* __restrict__ W0,
    const float* __restrict__ Wb, const float* __restrict__ bb,
    const float* __restrict__ Wo, const float* __restrict__ bo,
    float* __restrict__ grad, float s)
{
    __shared__ __align__(16) char hA[16384];
    __shared__ __align__(16) char hB[16384];
    __shared__ __align__(16) char hC[16384];
    const int tid = threadIdx.x, wid = tid >> 6, l = tid & 63;
    const int l15 = l & 15, l4 = l >> 4;
    const int colb = wid * 32;

    bf16x8 wfrag[2][2][4];   // [layer][ntg][kk]
    #pragma unroll
    for (int layer = 0; layer < 2; ++layer)
        #pragma unroll
        for (int ntg = 0; ntg < 2; ++ntg)
            #pragma unroll
            for (int kk = 0; kk < 4; ++kk) {
                bf16x8 f;
                #pragma unroll
                for (int e = 0; e < 8; ++e) {
                    int k = kk*32 + l4*8 + e;
                    int n = colb + ntg*16 + l15;
                    f[e] = (short)f2bf(Wb[layer*FD*FD + k*FD + n]);
                }
                wfrag[layer][ntg][kk] = f;
            }
    bf16x8 wofrag[4];        // Wo padded 128x16 (cols>=3 zero)
    #pragma unroll
    for (int kk = 0; kk < 4; ++kk) {
        bf16x8 f;
        #pragma unroll
        for (int e = 0; e < 8; ++e) {
            int k = kk*32 + l4*8 + e;
            f[e] = (short)(l15 < 3 ? f2bf(Wo[k*3 + l15]) : 0);
        }
        wofrag[kk] = f;
    }
    float w0c[3][2], bbv[2][2];
    #pragma unroll
    for (int ntg = 0; ntg < 2; ++ntg) {
        int col = colb + ntg*16 + l15;
        w0c[0][ntg] = W0[0*FD+col];
        w0c[1][ntg] = W0[1*FD+col];
        w0c[2][ntg] = W0[2*FD+col];
        bbv[0][ntg] = bb[col]; bbv[1][ntg] = bb[FD+col];
    }
    const float bol = (l15 < 3) ? bo[l15] : 0.f;

    for (int grp = blockIdx.x; grp < NGRP; grp += gridDim.x) {
        float hc[2][2][2][4];    // [t][rt][ntg][reg]
        // ---- P0: layer0 both tiles -> hA ----
        #pragma unroll
        for (int t = 0; t < 2; ++t) {
            char* hAt = hA + t*8192;
            const int pt0 = (grp*2 + t)*8;
            #pragma unroll
            for (int rt = 0; rt < 2; ++rt) {
                int p = pt0 + rt*4 + l4;
                int b = p >> 14, n = p & (NPT-1);
                float nx = noisy[p*3+0], ny = noisy[p*3+1], nz = noisy[p*3+2];
                float cx[4], cy[4], cz[4];
                #pragma unroll
                for (int k = 0; k < 4; ++k) {
                    int nb = n + k - 2;
                    nb = nb < 0 ? 0 : (nb > NPT-1 ? NPT-1 : nb);
                    int pn = (b << 14) + nb;
                    cx[k] = cur[pn*3+0] - nx;
                    cy[k] = cur[pn*3+1] - ny;
                    cz[k] = cur[pn*3+2] - nz;
                }
                #pragma unroll
                for (int ntg = 0; ntg < 2; ++ntg) {
                    int col = colb + ntg*16 + l15;
                    float fp = bf2f(fproj[(size_t)p*FD + col]);
                    #pragma unroll
                    for (int reg = 0; reg < 4; ++reg) {
                        float u = fp + cx[reg]*w0c[0][ntg] + cy[reg]*w0c[1][ntg] + cz[reg]*w0c[2][ntg];
                        u = fmaxf(u, 0.f);
                        hc[t][rt][ntg][reg] = u;
                        *(u16*)(hAt + swz(rt*16 + l4*4 + reg, col*2)) = f2bf(u);
                    }
                }
            }
        }
        __syncthreads();
        // ---- P1: layer1 both tiles -> hB ----
        #pragma unroll
        for (int t = 0; t < 2; ++t) {
            char* hAt = hA + t*8192;
            char* hBt = hB + t*8192;
            bf16x8 a[2][4];
            #pragma unroll
            for (int rt = 0; rt < 2; ++rt)
                #pragma unroll
                for (int kk = 0; kk < 4; ++kk)
                    a[rt][kk] = *(const bf16x8*)(hAt + swz(rt*16 + l15, kk*64 + l4*16));
            #pragma unroll
            for (int ntg = 0; ntg < 2; ++ntg) {
                f32x4 acc0 = {bbv[0][ntg],bbv[0][ntg],bbv[0][ntg],bbv[0][ntg]};
                f32x4 acc1 = acc0;
                #pragma unroll
                for (int kk = 0; kk < 4; ++kk) {
                    acc0 = __builtin_amdgcn_mfma_f32_16x16x32_bf16(a[0][kk], wfrag[0][ntg][kk], acc0, 0,0,0);
                    acc1 = __builtin_amdgcn_mfma_f32_16x16x32_bf16(a[1][kk], wfrag[0][ntg][kk], acc1, 0,0,0);
                }
                int col = colb + ntg*16 + l15;
                #pragma unroll
                for (int reg = 0; reg < 4; ++reg) {
                    hc[t][0][ntg][reg] += fmaxf(acc0[reg], 0.f);
                    hc[t][1][ntg][reg] += fmaxf(acc1[reg], 0.f);
                    *(u16*)(hBt + swz(l4*4+reg,    col*2)) = f2bf(hc[t][0][ntg][reg]);
                    *(u16*)(hBt + swz(16+l4*4+reg, col*2)) = f2bf(hc[t][1][ntg][reg]);
                }
            }
        }
        __syncthreads();
        // ---- P2: layer2 both tiles -> hC ----
        #pragma unroll
        for (int t = 0; t < 2; ++t) {
            char* hBt = hB + t*8192;
            char* hCt = hC + t*8192;
            bf16x8 a[2][4];
            #pragma unroll
            for (int rt = 0; rt < 2; ++rt)
                #pragma unroll
                for (int kk = 0; kk < 4; ++kk)
                    a[rt][kk] = *(const bf16x8*)(hBt + swz(rt*16 + l15, kk*64 + l4*16));
            #pragma unroll
            for (int ntg = 0; ntg < 2; ++ntg) {
                f32x4 acc0 = {bbv[1][ntg],bbv[1][ntg],bbv[1][ntg],bbv[1][ntg]};
                f32x4 acc1 = acc0;
                #pragma unroll
                for (int kk = 0; kk < 4; ++kk) {
                    acc0 = __builtin_amdgcn_mfma_f32_16x16x32_bf16(a[0][kk], wfrag[1][ntg][kk], acc0, 0,0,0);
                    acc1 = __builtin_amdgcn_mfma_f32_16x16x32_bf16(a[1][kk], wfrag[1][ntg][kk], acc1, 0,0,0);
                }
                int col = colb + ntg*16 + l15;
                #pragma unroll
                for (int reg = 0; reg < 4; ++reg) {
                    float h0 = hc[t][0][ntg][reg] + fmaxf(acc0[reg], 0.f);
                    float h1 = hc[t][1][ntg][reg] + fmaxf(acc1[reg], 0.f);
                    *(u16*)(hCt + swz(l4*4+reg,    col*2)) = f2bf(h0);
                    *(u16*)(hCt + swz(16+l4*4+reg, col*2)) = f2bf(h1);
                }
            }
        }
        __syncthreads();
        // ---- P3: epilogue, all 4 waves (2 per tile): grad = h@Wo, store ----
        {
            int t = wid >> 1, sub = wid & 1;
            const char* hCt = hC + t*8192;
            bf16x8 a[4];
            #pragma unroll
            for (int kk = 0; kk < 4; ++kk)
                a[kk] = *(const bf16x8*)(hCt + swz(sub*16 + l15, kk*64 + l4*16));
            f32x4 acc = {0.f,0.f,0.f,0.f};
            #pragma unroll
            for (int kk = 0; kk < 4; ++kk)
                acc = __builtin_amdgcn_mfma_f32_16x16x32_bf16(a[kk], wofrag[kk], acc, 0,0,0);
            if (l15 < 3) {
                int row0 = (grp*2 + t)*32 + sub*16 + l4*4;
                #pragma unroll
                for (int reg = 0; reg < 4; ++reg)
                    grad[(size_t)(row0 + reg)*3 + l15] = s*(acc[reg] + bol);
            }
        }
        // no barrier: hC next written in P2, guarded by P0/P1-end barriers
    }
}

// ---------------------------------------------------------------------------
// Gather (inverse of the clip-stencil scatter): dst[p] = cur[p] + sum(grad)
// grad row index = point*4 + k; contributions to p: (q=p+2-k, k) in-range,
// plus clip extras at n==0 and n==NPT-1.
// ---------------------------------------------------------------------------
__global__ __launch_bounds__(256) void gather_kernel(
    const float* __restrict__ cur, const float* __restrict__ grad,
    float* __restrict__ dst)
{
    int p = blockIdx.x*256 + threadIdx.x;
    if (p >= TOTP) return;
    int b = p >> 14, n = p & (NPT-1);
    float a0 = 0.f, a1 = 0.f, a2 = 0.f;
    #pragma unroll
    for (int k = 0; k < 4; ++k) {
        int nq = n + 2 - k;
        if (nq >= 0 && nq <= NPT-1) {
            const float* g = &grad[(size_t)(((b<<14) + nq)*4 + k)*3];
            a0 += g[0]; a1 += g[1]; a2 += g[2];
        }
    }
    if (n == 0) {
        const float* g0 = &grad[(size_t)((b<<14)*4 + 0)*3];
        const float* g1 = &grad[(size_t)((b<<14)*4 + 1)*3];
        const float* g2 = &grad[(size_t)(((b<<14)+1)*4 + 0)*3];
        a0 += g0[0] + g1[0] + g2[0];
        a1 += g0[1] + g1[1] + g2[1];
        a2 += g0[2] + g1[2] + g2[2];
    }
    if (n == NPT-1) {
        const float* g = &grad[(size_t)(((b<<14)+NPT-1)*4 + 3)*3];
        a0 += g[0]; a1 += g[1]; a2 += g[2];
    }
    dst[p*3+0] = cur[p*3+0] + a0;
    dst[p*3+1] = cur[p*3+1] + a1;
    dst[p*3+2] = cur[p*3+2] + a2;
}

extern "C" void kernel_launch(void* const* d_in, const int* in_sizes, int n_in,
                              void* d_out, int out_size, void* d_ws, size_t ws_size,
                              hipStream_t stream) {
    const float* pcl = (const float*)d_in[0];
    const float* Wf1 = (const float*)d_in[1];
    const float* bf1 = (const float*)d_in[2];
    const float* Wf2 = (const float*)d_in[3];
    const float* bf2 = (const float*)d_in[4];
    const float* W0  = (const float*)d_in[5];
    const float* b0  = (const float*)d_in[6];
    const float* Wb  = (const float*)d_in[7];
    const float* bb  = (const float*)d_in[8];
    const float* Wo  = (const float*)d_in[9];
    const float* bo  = (const float*)d_in[10];
    float* out = (float*)d_out;

    char* ws = (char*)d_ws;
    u16*   fproj = (u16*)ws;                                   // 8.4 MB
    float* grad  = (float*)(ws + (size_t)TOTP*FD*2);           // NROWS*3*4 = 1.5 MB
    float* bufA  = grad + (size_t)NROWS*3;
    float* bufB  = bufA + (size_t)TOTP*3;

    fproj_mfma<<<512, 256, 0, stream>>>(pcl, Wf1, bf1, Wf2, bf2, W0, b0, fproj);

    float s0 = 0.2f, s1 = s0*0.95f, s2 = s1*0.95f, s3 = s2*0.95f;
    step_mfma<<<768, 256, 0, stream>>>(pcl,  pcl, fproj, W0, Wb, bb, Wo, bo, grad, s0);
    gather_kernel<<<TOTP/256, 256, 0, stream>>>(pcl,  grad, bufA);
    step_mfma<<<768, 256, 0, stream>>>(bufA, pcl, fproj, W0, Wb, bb, Wo, bo, grad, s1);
    gather_kernel<<<TOTP/256, 256, 0, stream>>>(bufA, grad, bufB);
    step_mfma<<<768, 256, 0, stream>>>(bufB, pcl, fproj, W0, Wb, bb, Wo, bo, grad, s2);
    gather_kernel<<<TOTP/256, 256, 0, stream>>>(bufB, grad, bufA);
    step_mfma<<<768, 256, 0, stream>>>(bufA, pcl, fproj, W0, Wb, bb, Wo, bo, grad, s3);
    gather_kernel<<<TOTP/256, 256, 0, stream>>>(bufA, grad, out);
}

// Round 5
// 192.799 us; speedup vs baseline: 1.8777x; 1.8777x over previous
//
#include <hip/hip_runtime.h>

#define NPT    16384
#define TOTP   32768          // B*N
#define FD     128
#define CHK    64             // output points per block
#define FTILES (TOTP/32)
#define FGRP   (FTILES/2)     // 512

typedef unsigned short u16;
typedef __attribute__((ext_vector_type(8))) short bf16x8;
typedef __attribute__((ext_vector_type(4))) float f32x4;

__device__ __forceinline__ float bf2f(u16 u) {
    union { unsigned int i; float f; } v; v.i = ((unsigned int)u) << 16; return v.f;
}
__device__ __forceinline__ u16 f2bf(float f) {
    union { float f; unsigned int i; } v; v.f = f;
    unsigned int u = v.i;
    u = u + 0x7FFFu + ((u >> 16) & 1u);   // RNE
    return (u16)(u >> 16);
}
// 32x128 bf16 tile, row stride 256B, G4 XOR swizzle (conflict-free b128 col reads)
__device__ __forceinline__ int swz(int row, int colbyte) {
    return row*256 + (colbyte ^ ((row & 7) << 4));
}

// ---------------------------------------------------------------------------
// fproj[p][j] = b0[j] + feat[p] @ W0[3:]   (feat = relu(pcl@Wf1+bf1)@Wf2+bf2)
// (unchanged from round 3/4 — verified correct)
// ---------------------------------------------------------------------------
__global__ __launch_bounds__(256, 2) void fproj_mfma(
    const float* __restrict__ pcl, const float* __restrict__ Wf1,
    const float* __restrict__ bf1, const float* __restrict__ Wf2,
    const float* __restrict__ bf2, const float* __restrict__ W0,
    const float* __restrict__ b0, u16* __restrict__ fproj)
{
    __shared__ __align__(16) char hA[16384];
    __shared__ __align__(16) char hB[16384];
    const int tid = threadIdx.x, wid = tid >> 6, l = tid & 63;
    const int l15 = l & 15, l4 = l >> 4;
    const int colb = wid * 32;

    bf16x8 wfA[2][4], wfB[2][4];
    #pragma unroll
    for (int ntg = 0; ntg < 2; ++ntg)
        #pragma unroll
        for (int kk = 0; kk < 4; ++kk) {
            bf16x8 fa, fb;
            #pragma unroll
            for (int e = 0; e < 8; ++e) {
                int k = kk*32 + l4*8 + e;
                int n = colb + ntg*16 + l15;
                fa[e] = (short)f2bf(Wf2[k*FD + n]);
                fb[e] = (short)f2bf(W0[(3+k)*FD + n]);
            }
            wfA[ntg][kk] = fa; wfB[ntg][kk] = fb;
        }
    float wf1c[3][2], bf1v[2], bf2v[2], b0v[2];
    #pragma unroll
    for (int ntg = 0; ntg < 2; ++ntg) {
        int col = colb + ntg*16 + l15;
        wf1c[0][ntg] = Wf1[0*FD+col];
        wf1c[1][ntg] = Wf1[1*FD+col];
        wf1c[2][ntg] = Wf1[2*FD+col];
        bf1v[ntg] = bf1[col]; bf2v[ntg] = bf2[col]; b0v[ntg] = b0[col];
    }

    for (int grp = blockIdx.x; grp < FGRP; grp += gridDim.x) {
        #pragma unroll
        for (int t = 0; t < 2; ++t) {
            char* hAt = hA + t*8192;
            const int pt0 = (grp*2 + t)*32;
            #pragma unroll
            for (int rt = 0; rt < 2; ++rt)
                #pragma unroll
                for (int reg = 0; reg < 4; ++reg) {
                    int row = rt*16 + l4*4 + reg;
                    int p = pt0 + row;
                    float px = pcl[p*3+0], py = pcl[p*3+1], pz = pcl[p*3+2];
                    #pragma unroll
                    for (int ntg = 0; ntg < 2; ++ntg) {
                        float tv = bf1v[ntg] + px*wf1c[0][ntg] + py*wf1c[1][ntg] + pz*wf1c[2][ntg];
                        tv = fmaxf(tv, 0.f);
                        int col = colb + ntg*16 + l15;
                        *(u16*)(hAt + swz(row, col*2)) = f2bf(tv);
                    }
                }
        }
        __syncthreads();
        #pragma unroll
        for (int t = 0; t < 2; ++t) {
            char* hAt = hA + t*8192;
            char* hBt = hB + t*8192;
            bf16x8 a[2][4];
            #pragma unroll
            for (int rt = 0; rt < 2; ++rt)
                #pragma unroll
                for (int kk = 0; kk < 4; ++kk)
                    a[rt][kk] = *(const bf16x8*)(hAt + swz(rt*16 + l15, kk*64 + l4*16));
            #pragma unroll
            for (int ntg = 0; ntg < 2; ++ntg) {
                f32x4 acc0 = {bf2v[ntg],bf2v[ntg],bf2v[ntg],bf2v[ntg]};
                f32x4 acc1 = acc0;
                #pragma unroll
                for (int kk = 0; kk < 4; ++kk) {
                    acc0 = __builtin_amdgcn_mfma_f32_16x16x32_bf16(a[0][kk], wfA[ntg][kk], acc0, 0,0,0);
                    acc1 = __builtin_amdgcn_mfma_f32_16x16x32_bf16(a[1][kk], wfA[ntg][kk], acc1, 0,0,0);
                }
                int col = colb + ntg*16 + l15;
                #pragma unroll
                for (int reg = 0; reg < 4; ++reg) {
                    *(u16*)(hBt + swz(l4*4+reg,    col*2)) = f2bf(acc0[reg]);
                    *(u16*)(hBt + swz(16+l4*4+reg, col*2)) = f2bf(acc1[reg]);
                }
            }
        }
        __syncthreads();
        #pragma unroll
        for (int t = 0; t < 2; ++t) {
            char* hBt = hB + t*8192;
            const int pt0 = (grp*2 + t)*32;
            bf16x8 a[2][4];
            #pragma unroll
            for (int rt = 0; rt < 2; ++rt)
                #pragma unroll
                for (int kk = 0; kk < 4; ++kk)
                    a[rt][kk] = *(const bf16x8*)(hBt + swz(rt*16 + l15, kk*64 + l4*16));
            #pragma unroll
            for (int ntg = 0; ntg < 2; ++ntg) {
                f32x4 acc0 = {b0v[ntg],b0v[ntg],b0v[ntg],b0v[ntg]};
                f32x4 acc1 = acc0;
                #pragma unroll
                for (int kk = 0; kk < 4; ++kk) {
                    acc0 = __builtin_amdgcn_mfma_f32_16x16x32_bf16(a[0][kk], wfB[ntg][kk], acc0, 0,0,0);
                    acc1 = __builtin_amdgcn_mfma_f32_16x16x32_bf16(a[1][kk], wfB[ntg][kk], acc1, 0,0,0);
                }
                int col = colb + ntg*16 + l15;
                #pragma unroll
                for (int reg = 0; reg < 4; ++reg) {
                    fproj[(size_t)(pt0 + l4*4+reg)*FD + col]      = f2bf(acc0[reg]);
                    fproj[(size_t)(pt0 + 16 + l4*4+reg)*FD + col] = f2bf(acc1[reg]);
                }
            }
        }
        __syncthreads();
    }
}

// ---------------------------------------------------------------------------
// Fused 4-step denoise. Block owns 64 points + halo 12; positions/fproj/grads
// live in LDS. Step s: grad rows for q in [A-(13-3s), B+(14-3s)] (clipped),
// scatter s*(grad+bo) via LDS atomics into next-position buffer.
// ---------------------------------------------------------------------------
__global__ __launch_bounds__(256, 2) void fused_steps(
    const float* __restrict__ pcl, const u16* __restrict__ fproj,
    const float* __restrict__ W0, const float* __restrict__ Wb,
    const float* __restrict__ bb, const float* __restrict__ Wo,
    const float* __restrict__ bo, float* __restrict__ out)
{
    __shared__ __align__(16) u16   fpl[86*144];   // fproj tile, stride 144 u16 (288B)
    __shared__ __align__(16) float X0l[88*3];     // original pcl (noisy)
    __shared__ __align__(16) float Xal[88*3];
    __shared__ __align__(16) float Xbl[88*3];
    __shared__ __align__(16) char  hA[8192];
    __shared__ __align__(16) char  hB[8192];
    __shared__ __align__(16) char  hC[8192];

    const int tid = threadIdx.x, wid = tid >> 6, l = tid & 63;
    const int l15 = l & 15, l4 = l >> 4;
    const int colb = wid * 32;

    const int blk = blockIdx.x;
    const int b = blk >> 8, cidx = blk & 255;
    const int A = cidx * CHK, Bp = A + CHK - 1;
    const int elo  = (A - 12 < 0) ? 0 : A - 12;
    const int ehi  = (Bp + 12 > NPT-1) ? NPT-1 : Bp + 12;
    const int esz3 = (ehi - elo + 1) * 3;
    const int fqlo = (A - 10 < 0) ? 0 : A - 10;
    const int fqhi = (Bp + 11 > NPT-1) ? NPT-1 : Bp + 11;
    const int fqc  = fqhi - fqlo + 1;
    const size_t gb = (size_t)b * NPT;

    // ---- weight fragments (register/AGPR-resident) ----
    bf16x8 wfrag[2][2][4];
    #pragma unroll
    for (int layer = 0; layer < 2; ++layer)
        #pragma unroll
        for (int ntg = 0; ntg < 2; ++ntg)
            #pragma unroll
            for (int kk = 0; kk < 4; ++kk) {
                bf16x8 f;
                #pragma unroll
                for (int e = 0; e < 8; ++e) {
                    int k = kk*32 + l4*8 + e;
                    int n = colb + ntg*16 + l15;
                    f[e] = (short)f2bf(Wb[layer*FD*FD + k*FD + n]);
                }
                wfrag[layer][ntg][kk] = f;
            }
    bf16x8 wofrag[4];
    #pragma unroll
    for (int kk = 0; kk < 4; ++kk) {
        bf16x8 f;
        #pragma unroll
        for (int e = 0; e < 8; ++e) {
            int k = kk*32 + l4*8 + e;
            f[e] = (short)(l15 < 3 ? f2bf(Wo[k*3 + l15]) : 0);
        }
        wofrag[kk] = f;
    }
    float w0c[3][2], bbv[2][2];
    #pragma unroll
    for (int ntg = 0; ntg < 2; ++ntg) {
        int col = colb + ntg*16 + l15;
        w0c[0][ntg] = W0[0*FD+col];
        w0c[1][ntg] = W0[1*FD+col];
        w0c[2][ntg] = W0[2*FD+col];
        bbv[0][ntg] = bb[col]; bbv[1][ntg] = bb[FD+col];
    }
    const float bol = (l15 < 3) ? bo[l15] : 0.f;

    // ---- stage pcl + fproj into LDS ----
    for (int i = tid; i < esz3; i += 256) X0l[i] = pcl[(gb + elo)*3 + i];
    for (int i = tid; i < fqc*32; i += 256) {
        int r = i >> 5, c = i & 31;
        *(uint2*)&fpl[r*144 + c*4] = *(const uint2*)&fproj[(gb + fqlo + r)*FD + c*4];
    }
    __syncthreads();

    auto do_step = [&](const float* curl, float* nxtl, float sval, int qlo, int qhi) {
        for (int i = tid; i < esz3; i += 256) nxtl[i] = curl[i];
        __syncthreads();
        const int nt_ = (qhi - qlo + 8) >> 3;
        for (int t = 0; t < nt_; ++t) {
            const int qbase = qlo + t*8;
            float hc[2][2][4];
            // ---- P0: layer0 -> hA ----
            #pragma unroll
            for (int rt = 0; rt < 2; ++rt) {
                int q = qbase + rt*4 + l4; if (q > qhi) q = qhi;
                int qe = (q - elo)*3;
                float nx = X0l[qe], ny = X0l[qe+1], nz = X0l[qe+2];
                float cx[4], cy[4], cz[4];
                #pragma unroll
                for (int k = 0; k < 4; ++k) {
                    int nb = q + k - 2;
                    nb = nb < 0 ? 0 : (nb > NPT-1 ? NPT-1 : nb);
                    int te = (nb - elo)*3;
                    cx[k] = curl[te]   - nx;
                    cy[k] = curl[te+1] - ny;
                    cz[k] = curl[te+2] - nz;
                }
                #pragma unroll
                for (int ntg = 0; ntg < 2; ++ntg) {
                    int col = colb + ntg*16 + l15;
                    float fp = bf2f(fpl[(q - fqlo)*144 + col]);
                    #pragma unroll
                    for (int reg = 0; reg < 4; ++reg) {
                        float u = fp + cx[reg]*w0c[0][ntg] + cy[reg]*w0c[1][ntg] + cz[reg]*w0c[2][ntg];
                        u = fmaxf(u, 0.f);
                        hc[rt][ntg][reg] = u;
                        *(u16*)(hA + swz(rt*16 + l4*4 + reg, col*2)) = f2bf(u);
                    }
                }
            }
            __syncthreads();
            // ---- P1: layer1 -> hB ----
            {
                bf16x8 a[2][4];
                #pragma unroll
                for (int rt = 0; rt < 2; ++rt)
                    #pragma unroll
                    for (int kk = 0; kk < 4; ++kk)
                        a[rt][kk] = *(const bf16x8*)(hA + swz(rt*16 + l15, kk*64 + l4*16));
                #pragma unroll
                for (int ntg = 0; ntg < 2; ++ntg) {
                    f32x4 acc0 = {bbv[0][ntg],bbv[0][ntg],bbv[0][ntg],bbv[0][ntg]};
                    f32x4 acc1 = acc0;
                    #pragma unroll
                    for (int kk = 0; kk < 4; ++kk) {
                        acc0 = __builtin_amdgcn_mfma_f32_16x16x32_bf16(a[0][kk], wfrag[0][ntg][kk], acc0, 0,0,0);
                        acc1 = __builtin_amdgcn_mfma_f32_16x16x32_bf16(a[1][kk], wfrag[0][ntg][kk], acc1, 0,0,0);
                    }
                    int col = colb + ntg*16 + l15;
                    #pragma unroll
                    for (int reg = 0; reg < 4; ++reg) {
                        hc[0][ntg][reg] += fmaxf(acc0[reg], 0.f);
                        hc[1][ntg][reg] += fmaxf(acc1[reg], 0.f);
                        *(u16*)(hB + swz(l4*4+reg,    col*2)) = f2bf(hc[0][ntg][reg]);
                        *(u16*)(hB + swz(16+l4*4+reg, col*2)) = f2bf(hc[1][ntg][reg]);
                    }
                }
            }
            __syncthreads();
            // ---- P2: layer2 -> hC ----
            {
                bf16x8 a[2][4];
                #pragma unroll
                for (int rt = 0; rt < 2; ++rt)
                    #pragma unroll
                    for (int kk = 0; kk < 4; ++kk)
                        a[rt][kk] = *(const bf16x8*)(hB + swz(rt*16 + l15, kk*64 + l4*16));
                #pragma unroll
                for (int ntg = 0; ntg < 2; ++ntg) {
                    f32x4 acc0 = {bbv[1][ntg],bbv[1][ntg],bbv[1][ntg],bbv[1][ntg]};
                    f32x4 acc1 = acc0;
                    #pragma unroll
                    for (int kk = 0; kk < 4; ++kk) {
                        acc0 = __builtin_amdgcn_mfma_f32_16x16x32_bf16(a[0][kk], wfrag[1][ntg][kk], acc0, 0,0,0);
                        acc1 = __builtin_amdgcn_mfma_f32_16x16x32_bf16(a[1][kk], wfrag[1][ntg][kk], acc1, 0,0,0);
                    }
                    int col = colb + ntg*16 + l15;
                    #pragma unroll
                    for (int reg = 0; reg < 4; ++reg) {
                        float h0 = hc[0][ntg][reg] + fmaxf(acc0[reg], 0.f);
                        float h1 = hc[1][ntg][reg] + fmaxf(acc1[reg], 0.f);
                        *(u16*)(hC + swz(l4*4+reg,    col*2)) = f2bf(h0);
                        *(u16*)(hC + swz(16+l4*4+reg, col*2)) = f2bf(h1);
                    }
                }
            }
            __syncthreads();
            // ---- P3: grad = h@Wo (+bo), LDS-atomic scatter (waves 0,1) ----
            if (wid < 2) {
                const int sub = wid;
                bf16x8 a[4];
                #pragma unroll
                for (int kk = 0; kk < 4; ++kk)
                    a[kk] = *(const bf16x8*)(hC + swz(sub*16 + l15, kk*64 + l4*16));
                f32x4 acc = {0.f,0.f,0.f,0.f};
                #pragma unroll
                for (int kk = 0; kk < 4; ++kk)
                    acc = __builtin_amdgcn_mfma_f32_16x16x32_bf16(a[kk], wofrag[kk], acc, 0,0,0);
                int q = qbase + sub*4 + l4;
                if (l15 < 3 && q <= qhi) {
                    #pragma unroll
                    for (int reg = 0; reg < 4; ++reg) {
                        int nb = q + reg - 2;
                        nb = nb < 0 ? 0 : (nb > NPT-1 ? NPT-1 : nb);
                        atomicAdd(&nxtl[(nb - elo)*3 + l15], sval*(acc[reg] + bol));
                    }
                }
            }
            // no barrier: hA rewrite next tile is safe (readers passed P1 barrier)
        }
        __syncthreads();   // all scatters complete before next step
    };

    const int q1lo = fqlo,                          q1hi = fqhi;
    const int q2lo = (A-7  < 0) ? 0 : A-7,          q2hi = (Bp+8 > NPT-1) ? NPT-1 : Bp+8;
    const int q3lo = (A-4  < 0) ? 0 : A-4,          q3hi = (Bp+5 > NPT-1) ? NPT-1 : Bp+5;
    const int q4lo = (A-1  < 0) ? 0 : A-1,          q4hi = (Bp+2 > NPT-1) ? NPT-1 : Bp+2;

    do_step(X0l, Xal, 0.2f,      q1lo, q1hi);
    do_step(Xal, Xbl, 0.19f,     q2lo, q2hi);
    do_step(Xbl, Xal, 0.1805f,   q3lo, q3hi);
    do_step(Xal, Xbl, 0.171475f, q4lo, q4hi);

    // ---- write owned span ----
    for (int i = tid; i < CHK*3; i += 256)
        out[(gb + A)*3 + i] = Xbl[(A - elo)*3 + i];
}

extern "C" void kernel_launch(void* const* d_in, const int* in_sizes, int n_in,
                              void* d_out, int out_size, void* d_ws, size_t ws_size,
                              hipStream_t stream) {
    const float* pcl = (const float*)d_in[0];
    const float* Wf1 = (const float*)d_in[1];
    const float* bf1 = (const float*)d_in[2];
    const float* Wf2 = (const float*)d_in[3];
    const float* bf2 = (const float*)d_in[4];
    const float* W0  = (const float*)d_in[5];
    const float* b0  = (const float*)d_in[6];
    const float* Wb  = (const float*)d_in[7];
    const float* bb  = (const float*)d_in[8];
    const float* Wo  = (const float*)d_in[9];
    const float* bo  = (const float*)d_in[10];
    float* out = (float*)d_out;

    u16* fproj = (u16*)d_ws;   // TOTP*FD*2 = 8.4 MB

    fproj_mfma<<<512, 256, 0, stream>>>(pcl, Wf1, bf1, Wf2, bf2, W0, b0, fproj);
    fused_steps<<<512, 256, 0, stream>>>(pcl, fproj, W0, Wb, bb, Wo, bo, out);
}